// Round 8
// baseline (4146.674 us; speedup 1.0000x reference)
//
#include <hip/hip_runtime.h>

// Persistent pipelined 2-layer LSTM for MI355X (gfx950).
// R8: critical path = h-recurrence only.
//  - 256 WGs x 512 threads; blocks 0..127 layer 0, 128..255 layer 1 (skew 2).
//  - 8 waves/WG: per ntile (16 batches): 2 x-waves (K-halves of x-part, both
//    M-tiles) + 2 h-waves (full K=1024, one M-tile each).
//  - x-partials for step t+1 computed during window t into LDS (double buffer)
//    -> x off the critical path (layer-1 x = O0 slot t+2, available 1 window
//    early thanks to the skew-2).
//  - h-waves: full-K -> no cross-wave reduction, no pre-epilogue syncthreads.
//  - arrive: 4 h-waves combine via LDS atomic; last does one agent-scope add
//    (32 stripes x 8 WGs). Master poll-wave aggregates stripes with 32 lanes,
//    then 16 lanes store 16 REPLICATED release copies (16 WGs/line).
//  - h publish sc1 (write-through to LLC); consume plain-cached (write-once
//    slots + launch-boundary L2 invalidate => never stale).
// Bounded spins + abort flag: failure = fast reported absmax, not a hang.

typedef unsigned short ushort_t;
typedef unsigned long long u64_t;
typedef __attribute__((ext_vector_type(8))) short short8;   // 8 bf16 MFMA operand
typedef __attribute__((ext_vector_type(4))) float f32x4;

#define NWG       256
#define NTHREADS  512
#define SEQ       512
#define HSLOT     32768        // 32*1024 elements per time slot
#define FULLSLOTS 513          // slot 0 = zeros, slot t+1 = h after step t
#define NSTRIPE   32
#define SSTRIDE   64           // stripe spacing in u32 (256 B): idx 0..1984
#define NREL      16
#define RELBASE   2048         // release copies at 2048 + i*32 (128 B apart)
#define RSTRIDE   32
#define ABORT_IDX 3072         // own cache line
#define CNT_BYTES 16384
#define POLL_MAX  8192         // ~2.7 ms @ ~800cyc/poll, then abort

__device__ __forceinline__ ushort_t f2bf(float f) {
  unsigned u = __builtin_bit_cast(unsigned, f);
  u += 0x7FFFu + ((u >> 16) & 1u);      // round-to-nearest-even
  return (ushort_t)(u >> 16);
}

__device__ __forceinline__ short8 pack_bf8(f32x4 a, f32x4 b) {
  short8 r;
  r[0] = (short)f2bf(a[0]); r[1] = (short)f2bf(a[1]);
  r[2] = (short)f2bf(a[2]); r[3] = (short)f2bf(a[3]);
  r[4] = (short)f2bf(b[0]); r[5] = (short)f2bf(b[1]);
  r[6] = (short)f2bf(b[2]); r[7] = (short)f2bf(b[3]);
  return r;
}

__device__ __forceinline__ float sigm(float x) { return 1.0f / (1.0f + __expf(-x)); }
__device__ __forceinline__ float fast_tanh(float x) {
  x = fminf(fmaxf(x, -15.f), 15.f);
  float e = __expf(-2.0f * x);
  return (1.0f - e) / (1.0f + e);
}

// One barrier epoch. h-waves (2,3,6,7) have already drained their publishes
// (vmcnt 0) before calling. lane0 of each h-wave combines via LDS; the 4th
// does the single agent-scope arrive. Poll wave = wave 2.
__device__ __forceinline__ void epoch_barrier(unsigned* cnt, unsigned* hcount,
                                              unsigned epoch, bool master) {
  const int wave = threadIdx.x >> 6;
  const int lane = threadIdx.x & 63;

  if ((wave & 2) && lane == 0) {
    unsigned old = atomicAdd(hcount, 1u);          // LDS combine, monotonic
    if ((old & 3u) == 3u)
      __hip_atomic_fetch_add(cnt + (blockIdx.x & (NSTRIPE - 1)) * SSTRIDE, 1u,
                             __ATOMIC_RELAXED, __HIP_MEMORY_SCOPE_AGENT);
  }

  if (wave == 2) {
    if (master) {
      if (lane < NSTRIPE) {
        const unsigned tgt = epoch * (NWG / NSTRIPE);
        for (int it = 0;; ++it) {
          if (__hip_atomic_load(cnt + lane * SSTRIDE,
                                __ATOMIC_RELAXED, __HIP_MEMORY_SCOPE_AGENT) >= tgt) break;
          if ((it & 63) == 63 &&
              __hip_atomic_load(cnt + ABORT_IDX,
                                __ATOMIC_RELAXED, __HIP_MEMORY_SCOPE_AGENT) != 0) break;
          if (it >= POLL_MAX) {
            __hip_atomic_store(cnt + ABORT_IDX, 1u,
                               __ATOMIC_RELAXED, __HIP_MEMORY_SCOPE_AGENT);
            break;
          }
          __builtin_amdgcn_s_sleep(1);
        }
      }
      // lanes reconverged: all stripes at target -> replicate release
      if (lane < NREL)
        __hip_atomic_store(cnt + RELBASE + lane * RSTRIDE, epoch,
                           __ATOMIC_RELAXED, __HIP_MEMORY_SCOPE_AGENT);
    } else {
      if (lane == 0) {
        const unsigned* rel = cnt + RELBASE + (blockIdx.x & (NREL - 1)) * RSTRIDE;
        for (int it = 0;; ++it) {
          if (__hip_atomic_load(rel, __ATOMIC_RELAXED, __HIP_MEMORY_SCOPE_AGENT) >= epoch) break;
          if ((it & 63) == 63 &&
              __hip_atomic_load(cnt + ABORT_IDX,
                                __ATOMIC_RELAXED, __HIP_MEMORY_SCOPE_AGENT) != 0) break;
          if (it >= POLL_MAX) {
            __hip_atomic_store(cnt + ABORT_IDX, 1u,
                               __ATOMIC_RELAXED, __HIP_MEMORY_SCOPE_AGENT);
            break;
          }
          __builtin_amdgcn_s_sleep(1);
        }
      }
    }
  }
  __syncthreads();   // window boundary: release observed + LDS xbuf visible
}

// One layer, SEQ+1 windows (one barrier each).
//   window w: x-waves compute x-partials for step w (into xbuf[w&1]);
//             h-waves run step t=w-1 (consume xbuf[(w-1)&1], full-K h MFMA,
//             epilogue, sc1 publish of h slot t+1, drain, arrive).
// MFMA 16x16x32: A row m: gate=m&3, unit=unit_base+mt*4+(m>>2).
// C/D: col = lane&15 (=batch), row = (lane>>4)*4 + reg -> reg = gate.
template<int KX, bool XFP32>
__device__ __forceinline__ void run_layer(
    const void* xsrc, long x_step, long x_bstride,
    const ushort_t* __restrict__ hbuf, ushort_t* __restrict__ hbuf_w,
    const float* __restrict__ W, int ldw,
    const float* __restrict__ bias,
    float* __restrict__ out, int out_h_off, int out_c_off, int write_last,
    float* xbuf, unsigned* cnt, unsigned* hcount,
    unsigned& epoch, int unit_base, bool master)
{
  constexpr int XCH = (KX / 2) / 32;                // x chunks per x-wave
  const int lane  = threadIdx.x & 63;
  const int wave  = threadIdx.x >> 6;               // 0..7
  const int ntile = wave >> 2;                      // 0,1
  const int r     = wave & 3;                       // 0,1: x-waves; 2,3: h-waves
  const bool isH  = r >= 2;
  const int wrow  = lane & 15;                      // A-frag row within M-tile
  const int koff  = (lane >> 4) * 8;                // A/B-frag k offset (elements)
  const int bb    = ntile * 16 + (lane & 15);       // batch (B row / D col)

  if (!isH) {
    // ---------------- x-wave: K-half `r`, both M-tiles ----------------
    const int kbase = r * (KX / 2);
    short8 wreg[2][16];
    #pragma unroll
    for (int mt = 0; mt < 2; ++mt) {
      const int grow = (wrow & 3) * 1024 + unit_base + mt * 4 + (wrow >> 2);
      const float* ws = W + (long)grow * ldw + kbase + koff;
      #pragma unroll
      for (int ch = 0; ch < 16; ++ch) {
        if (ch < XCH) {
          f32x4 v0 = *(const f32x4*)(ws + ch * 32);
          f32x4 v1 = *(const f32x4*)(ws + ch * 32 + 4);
          wreg[mt][ch] = pack_bf8(v0, v1);
        }
      }
    }

    for (int w = 0; w <= SEQ; ++w) {
      if (w < SEQ) {
        const int s = w;                             // compute x-part of step s
        f32x4 acc[2] = {{0.f,0.f,0.f,0.f},{0.f,0.f,0.f,0.f}};
        if constexpr (XFP32) {
          const float* bp = (const float*)xsrc + (long)s * x_step
                            + (long)bb * x_bstride + kbase + koff;
          f32x4 xv[2 * XCH];
          #pragma unroll
          for (int ch = 0; ch < XCH; ++ch) {
            xv[2*ch]   = *(const f32x4*)(bp + ch * 32);
            xv[2*ch+1] = *(const f32x4*)(bp + ch * 32 + 4);
          }
          #pragma unroll
          for (int ch = 0; ch < XCH; ++ch) {
            short8 bf = pack_bf8(xv[2*ch], xv[2*ch+1]);
            acc[0] = __builtin_amdgcn_mfma_f32_16x16x32_bf16(wreg[0][ch], bf, acc[0], 0, 0, 0);
            acc[1] = __builtin_amdgcn_mfma_f32_16x16x32_bf16(wreg[1][ch], bf, acc[1], 0, 0, 0);
          }
        } else {
          const ushort_t* bp = (const ushort_t*)xsrc + (long)s * x_step
                               + (long)bb * x_bstride + kbase + koff;
          short8 xv[16];
          #pragma unroll
          for (int ch = 0; ch < 16; ++ch) xv[ch] = *(const short8*)(bp + ch * 32);
          #pragma unroll
          for (int ch = 0; ch < 16; ++ch) {
            acc[0] = __builtin_amdgcn_mfma_f32_16x16x32_bf16(wreg[0][ch], xv[ch], acc[0], 0, 0, 0);
            acc[1] = __builtin_amdgcn_mfma_f32_16x16x32_bf16(wreg[1][ch], xv[ch], acc[1], 0, 0, 0);
          }
        }
        #pragma unroll
        for (int mt = 0; mt < 2; ++mt)
          *(f32x4*)&xbuf[(((((s & 1) * 2 + ntile) * 2 + r) * 2 + mt) * 64 + lane) * 4] = acc[mt];
      }
      ++epoch;
      epoch_barrier(cnt, hcount, epoch, master);
    }

  } else {
    // ---------------- h-wave: full K=1024, M-tile (r-2) ----------------
    const int mt = r - 2;
    short8 wreg[32];
    {
      const int grow = (wrow & 3) * 1024 + unit_base + mt * 4 + (wrow >> 2);
      const float* ws = W + (long)grow * ldw + KX + koff;
      #pragma unroll
      for (int ch = 0; ch < 32; ++ch) {
        f32x4 v0 = *(const f32x4*)(ws + ch * 32);
        f32x4 v1 = *(const f32x4*)(ws + ch * 32 + 4);
        wreg[ch] = pack_bf8(v0, v1);
      }
    }
    const int u = unit_base + mt * 4 + (lane >> 4);
    const float bI = bias[u],        bF = bias[1024 + u];
    const float bG = bias[2048 + u], bO = bias[3072 + u];
    float c = 0.0f;

    for (int w = 0; w <= SEQ; ++w) {
      if (w >= 1) {
        const int t = w - 1;
        const ushort_t* bp = hbuf + (long)t * HSLOT + (long)bb * 1024 + koff;
        f32x4 acc = {0.f, 0.f, 0.f, 0.f};
        short8 hv[16];
        #pragma unroll
        for (int ch = 0; ch < 16; ++ch) hv[ch] = *(const short8*)(bp + ch * 32);
        #pragma unroll
        for (int ch = 0; ch < 16; ++ch)
          acc = __builtin_amdgcn_mfma_f32_16x16x32_bf16(wreg[ch], hv[ch], acc, 0, 0, 0);
        #pragma unroll
        for (int ch = 0; ch < 16; ++ch) hv[ch] = *(const short8*)(bp + (16 + ch) * 32);
        #pragma unroll
        for (int ch = 0; ch < 16; ++ch)
          acc = __builtin_amdgcn_mfma_f32_16x16x32_bf16(wreg[16 + ch], hv[ch], acc, 0, 0, 0);

        // add x-partials (computed last window; visible via barrier syncthreads)
        acc += *(const f32x4*)&xbuf[(((((t & 1) * 2 + ntile) * 2 + 0) * 2 + mt) * 64 + lane) * 4];
        acc += *(const f32x4*)&xbuf[(((((t & 1) * 2 + ntile) * 2 + 1) * 2 + mt) * 64 + lane) * 4];

        float pi = acc[0] + bI, pf = acc[1] + bF;
        float pg = acc[2] + bG, po = acc[3] + bO;
        float ig = sigm(pi), fg = sigm(pf), gg = fast_tanh(pg), og = sigm(po);
        c = fg * c + ig * gg;
        float h = og * fast_tanh(c);

        // pack 4 units/batch in-register: lane L<16 gathers L, L+16, L+32, L+48
        unsigned v  = f2bf(h);
        unsigned v1 = __shfl((int)v, (lane & 15) + 16);
        unsigned v2 = __shfl((int)v, (lane & 15) + 32);
        unsigned v3 = __shfl((int)v, (lane & 15) + 48);

        if (t == SEQ - 1) {
          out[out_h_off + bb * 1024 + u] = h;      // h_n[layer]
          out[out_c_off + bb * 1024 + u] = c;      // c_n[layer]
          if (write_last) out[bb * 1024 + u] = h;  // out1[:, -1, :]
        }

        if (lane < 16) {
          u64_t val = (u64_t)(v & 0xFFFFu) | ((u64_t)(v1 & 0xFFFFu) << 16)
                    | ((u64_t)(v2 & 0xFFFFu) << 32) | ((u64_t)(v3 & 0xFFFFu) << 48);
          u64_t* dst = (u64_t*)(hbuf_w + (long)(t + 1) * HSLOT
                                + (long)bb * 1024 + unit_base + mt * 4);
          __hip_atomic_store(dst, val, __ATOMIC_RELAXED, __HIP_MEMORY_SCOPE_AGENT);
        }
        asm volatile("s_waitcnt vmcnt(0)" ::: "memory");   // drain publish (wave-wide)
      }
      ++epoch;
      epoch_barrier(cnt, hcount, epoch, master);
    }
  }
}

__global__ __launch_bounds__(NTHREADS, 2)
void lstm_persistent(const float* __restrict__ x,  const float* __restrict__ W0,
                     const float* __restrict__ b0, const float* __restrict__ W1,
                     const float* __restrict__ b1, float* __restrict__ out,
                     unsigned* cnt, ushort_t* O0, ushort_t* H1)
{
  __shared__ float    xbuf[4096];   // [buf2][ntile2][xsub2][mt2][64][4] = 16 KB
  __shared__ unsigned hcount;       // monotonic h-wave arrive combiner
  unsigned epoch = 0;
  const int  role      = (int)(blockIdx.x >> 7);      // 0: layer0, 1: layer1
  const int  unit_base = (int)(blockIdx.x & 127) * 8;
  const bool master    = (blockIdx.x == 0);

  if (threadIdx.x == 0) hcount = 0;

  // zero slot 0 of both h buffers (initial hidden state), device-visible (sc1)
  int gtid = (int)blockIdx.x * NTHREADS + threadIdx.x;
  if (gtid < 16384) {
    __hip_atomic_store((unsigned*)O0 + gtid, 0u, __ATOMIC_RELAXED, __HIP_MEMORY_SCOPE_AGENT);
    __hip_atomic_store((unsigned*)H1 + gtid, 0u, __ATOMIC_RELAXED, __HIP_MEMORY_SCOPE_AGENT);
  }
  asm volatile("s_waitcnt vmcnt(0)" ::: "memory");
  __syncthreads();   // drains + hcount init before any arrive
  ++epoch;
  epoch_barrier(cnt, &hcount, epoch, master);        // epoch 1

  if (role == 0) {
    // layer 0: windows at epochs 2..514 (513 barriers), then 2 trailing idles
    run_layer<512, true>(x, 512, 262144,
                         O0, O0, W0, 1536, b0,
                         out, 32768, 98304, 0,
                         xbuf, cnt, &hcount, epoch, unit_base, master);
    ++epoch; epoch_barrier(cnt, &hcount, epoch, master);   // 515
    ++epoch; epoch_barrier(cnt, &hcount, epoch, master);   // 516
  } else {
    // layer 1: skew 2 (idle epochs 2,3), windows at epochs 4..516.
    // x-wave window w reads O0 slot w+1 (published at epoch w+3 <= current-1);
    // h-step t consumes H1 slot t (own, 1 window earlier) + xbuf from window t.
    ++epoch; epoch_barrier(cnt, &hcount, epoch, false);    // 2
    ++epoch; epoch_barrier(cnt, &hcount, epoch, false);    // 3
    run_layer<1024, false>((const void*)(O0 + HSLOT), HSLOT, 1024,
                           H1, H1, W1, 2048, b1,
                           out, 65536, 131072, 1,
                           xbuf, cnt, &hcount, epoch, unit_base, false);
  }
}

extern "C" void kernel_launch(void* const* d_in, const int* in_sizes, int n_in,
                              void* d_out, int out_size, void* d_ws, size_t ws_size,
                              hipStream_t stream) {
  (void)in_sizes; (void)n_in; (void)out_size;

  const float* x  = (const float*)d_in[0];
  const float* W0 = (const float*)d_in[1];
  const float* b0 = (const float*)d_in[2];
  const float* W1 = (const float*)d_in[3];
  const float* b1 = (const float*)d_in[4];
  float* out = (float*)d_out;

  // workspace layout:
  //   [0, 16K)            barrier stripes (32x256B) + 16 release copies + abort
  //   [16K, +513*64KB)    O0: layer-0 h, full 513 slots (write-once)
  //   [.., +513*64KB)     H1: layer-1 h, full 513 slots (write-once)
  const size_t o0_bytes = (size_t)FULLSLOTS * HSLOT * sizeof(ushort_t);
  const size_t need     = CNT_BYTES + 2 * o0_bytes;
  if (ws_size < need) return;  // wrong answer -> absmax signal, not a hang

  unsigned* cnt = (unsigned*)d_ws;
  ushort_t* O0  = (ushort_t*)((char*)d_ws + CNT_BYTES);
  ushort_t* H1  = O0 + (size_t)FULLSLOTS * HSLOT;

  hipMemsetAsync(d_ws, 0, CNT_BYTES, stream);

  lstm_persistent<<<dim3(NWG), dim3(NTHREADS), 0, stream>>>(
      x, W0, b0, W1, b1, out, cnt, O0, H1);
}

// Round 9
// 3207.127 us; speedup vs baseline: 1.2930x; 1.2930x over previous
//
#include <hip/hip_runtime.h>

// Persistent pipelined 2-layer LSTM for MI355X (gfx950).
// R9: R7's split-K h-waves + R8's x-prefetch + per-layer decoupled barriers.
//  - 256 WGs x 512 threads; blocks 0..127 layer 0, 128..255 layer 1.
//  - waves: ntile = wave>>2 (batch 16-tile), r = wave&3:
//      r 0,1 -> h-waves (K-halves of the recurrent part, both M-tiles;
//               r1 runs the epilogue), r 2,3 -> x-waves (K-halves of x-part).
//  - window w: h-waves run step t=w-1; x-waves compute x-partials for step w
//    into LDS xbuf (double buffer) AFTER the mid sync -> hidden under the poll.
//  - per-LAYER barrier: arrives from the 2 epilogue waves (LDS-combined to one
//    agent RMW), 16 stripes x 8 WGs; layer-master polls stripes with 16 lanes,
//    stores 16 replicated release words. Cross-layer edge: layer-1 WGs poll
//    layer-0's release replicas (release e => O0 slot e-2 published).
//  - h publish sc1 (write-through to LLC); consume plain-cached (write-once
//    slots + launch-boundary L2 invalidate => never stale).
// Bounded sleep-free spins + abort flag: failure = fast reported absmax.

typedef unsigned short ushort_t;
typedef unsigned long long u64_t;
typedef __attribute__((ext_vector_type(8))) short short8;   // 8 bf16 MFMA operand
typedef __attribute__((ext_vector_type(4))) float f32x4;

#define NWG       256
#define NTHREADS  512
#define SEQ       512
#define HSLOT     32768        // 32*1024 elements per time slot
#define FULLSLOTS 513
#define LBASE     4096         // per-layer counter region, u32 units (16 KB)
#define RELOFF    2048         // release replicas at base+2048+i*32 (128B apart)
#define ABORT_U32 8128         // one global abort word
#define CNT_BYTES 32768
#define POLL_MAX  20000        // ~5 ms @ ~600cyc/poll, then abort

__device__ __forceinline__ ushort_t f2bf(float f) {
  unsigned u = __builtin_bit_cast(unsigned, f);
  u += 0x7FFFu + ((u >> 16) & 1u);      // round-to-nearest-even
  return (ushort_t)(u >> 16);
}

__device__ __forceinline__ short8 pack_bf8(f32x4 a, f32x4 b) {
  short8 r;
  r[0] = (short)f2bf(a[0]); r[1] = (short)f2bf(a[1]);
  r[2] = (short)f2bf(a[2]); r[3] = (short)f2bf(a[3]);
  r[4] = (short)f2bf(b[0]); r[5] = (short)f2bf(b[1]);
  r[6] = (short)f2bf(b[2]); r[7] = (short)f2bf(b[3]);
  return r;
}

__device__ __forceinline__ float sigm(float x) { return 1.0f / (1.0f + __expf(-x)); }
__device__ __forceinline__ float fast_tanh(float x) {
  x = fminf(fmaxf(x, -15.f), 15.f);
  float e = __expf(-2.0f * x);
  return (1.0f - e) / (1.0f + e);
}

// Per-layer barrier epoch. Arrive: epilogue waves (1,5) lane0 LDS-combine; the
// 2nd does one agent-scope RMW on stripe (lidx&15). Wave 0 polls:
//   master: lanes 0..15 poll the 16 stripes (target e*8), then 16 lanes store
//           replicated release = e.  non-master: lane 0 polls own release.
//   lane 17 (both): polls OTHER layer's release >= progThresh (0 = skip).
// All conditions polled in ONE sleep-free loop (parallel lanes).
__device__ __forceinline__ void bar_epoch(unsigned* cntOwn, unsigned* relOther,
                                          unsigned* abortp, unsigned* hcount,
                                          unsigned e, bool master, int lidx,
                                          unsigned progThresh) {
  const int wave = threadIdx.x >> 6;
  const int lane = threadIdx.x & 63;

  if ((wave == 1 || wave == 5) && lane == 0) {
    unsigned old = atomicAdd(hcount, 1u);          // LDS combine, monotonic
    if (old & 1u)
      __hip_atomic_fetch_add(cntOwn + (lidx & 15) * 64, 1u,
                             __ATOMIC_RELAXED, __HIP_MEMORY_SCOPE_AGENT);
  }

  if (wave == 0) {
    const unsigned* addr = nullptr;
    unsigned tgt = 0;
    if (master) {
      if (lane < 16) { addr = cntOwn + lane * 64; tgt = e * 8u; }
    } else {
      if (lane == 0) { addr = cntOwn + RELOFF + (lidx & 15) * 32; tgt = e; }
    }
    if (lane == 17 && progThresh) {
      addr = relOther + (lidx & 15) * 32; tgt = progThresh;
    }
    if (addr) {
      for (int it = 0;; ++it) {
        if (__hip_atomic_load(addr, __ATOMIC_RELAXED, __HIP_MEMORY_SCOPE_AGENT) >= tgt) break;
        if ((it & 31) == 31 &&
            __hip_atomic_load(abortp, __ATOMIC_RELAXED, __HIP_MEMORY_SCOPE_AGENT) != 0) break;
        if (it >= POLL_MAX) {
          __hip_atomic_store(abortp, 1u, __ATOMIC_RELAXED, __HIP_MEMORY_SCOPE_AGENT);
          break;
        }
      }
    }
    if (master && lane < 16)
      __hip_atomic_store(cntOwn + RELOFF + lane * 32, e,
                         __ATOMIC_RELAXED, __HIP_MEMORY_SCOPE_AGENT);
  }
  __syncthreads();   // window boundary
}

// One layer: 513 windows (w=0..512), barrier epoch e=w+2 after each.
//   window w: h-waves run step t=w-1 (w>=1); x-waves compute x-part of step
//   s=w (s<SEQ) into xbuf[s&1] AFTER the mid sync (hidden under the poll).
// MFMA 16x16x32: A row m: gate=m&3, unit=ub+mt*4+(m>>2).
// C/D: col = lane&15 (=batch), row = (lane>>4)*4 + reg -> reg = gate.
template<int KX, bool XFP32, bool ISL1>
__device__ __forceinline__ void run_layer(
    const void* xsrc, long x_step, long x_bstride,
    const ushort_t* __restrict__ hbuf, ushort_t* __restrict__ hbuf_w,
    const float* __restrict__ W, int ldw,
    const float* __restrict__ bias,
    float* __restrict__ out, int out_h_off, int out_c_off, int write_last,
    float* xbuf, float* red, unsigned* hcount,
    unsigned* cntOwn, unsigned* relOther, unsigned* abortp,
    int lidx, int ub, bool master)
{
  constexpr int XCH = (KX / 2) / 32;                // x chunks per x-wave
  const int lane  = threadIdx.x & 63;
  const int wave  = threadIdx.x >> 6;               // 0..7
  const int ntile = wave >> 2;                      // 0,1
  const int r     = wave & 3;                       // 0,1: h-waves; 2,3: x-waves
  const bool isH  = r < 2;
  const int sub   = r & 1;
  const int wrow  = lane & 15;
  const int koff  = (lane >> 4) * 8;                // frag k offset (elements)
  const int bb    = ntile * 16 + (lane & 15);       // batch

  // ---- pin weight fragments (bf16), 2 M-tiles per wave ----
  const int kbase = isH ? (KX + sub * 512) : ((r - 2) * (KX / 2));
  const int mych  = isH ? 16 : XCH;
  short8 wreg[2][16];
  #pragma unroll
  for (int mt = 0; mt < 2; ++mt) {
    const int grow = (wrow & 3) * 1024 + ub + mt * 4 + (wrow >> 2);
    const float* ws = W + (long)grow * ldw + kbase + koff;
    #pragma unroll
    for (int ch = 0; ch < 16; ++ch) {
      if (ch < mych) {
        f32x4 v0 = *(const f32x4*)(ws + ch * 32);
        f32x4 v1 = *(const f32x4*)(ws + ch * 32 + 4);
        wreg[mt][ch] = pack_bf8(v0, v1);
      }
    }
  }

  const int u0 = ub + (lane >> 4);
  float bI[2], bF[2], bG[2], bO[2], c[2] = {0.f, 0.f};
  #pragma unroll
  for (int mt = 0; mt < 2; ++mt) {
    const int u = u0 + mt * 4;
    bI[mt] = bias[u];        bF[mt] = bias[1024 + u];
    bG[mt] = bias[2048 + u]; bO[mt] = bias[3072 + u];
  }

  for (int w = 0; w <= SEQ; ++w) {
    const int t = w - 1;
    f32x4 acc[2] = {{0.f,0.f,0.f,0.f},{0.f,0.f,0.f,0.f}};

    if (isH && w >= 1) {
      // h K-half: 16x16B loads in one flight, 32 MFMAs (2 M-tiles)
      const ushort_t* bp = hbuf + (long)t * HSLOT + (long)bb * 1024 + sub * 512 + koff;
      short8 hv[16];
      #pragma unroll
      for (int ch = 0; ch < 16; ++ch) hv[ch] = *(const short8*)(bp + ch * 32);
      #pragma unroll
      for (int ch = 0; ch < 16; ++ch) {
        acc[0] = __builtin_amdgcn_mfma_f32_16x16x32_bf16(wreg[0][ch], hv[ch], acc[0], 0, 0, 0);
        acc[1] = __builtin_amdgcn_mfma_f32_16x16x32_bf16(wreg[1][ch], hv[ch], acc[1], 0, 0, 0);
      }
      if (sub == 0) {
        #pragma unroll
        for (int mt = 0; mt < 2; ++mt)
          *(f32x4*)&red[((ntile * 2 + mt) * 64 + lane) * 4] = acc[mt];
      }
    }

    __syncthreads();   // A: red ready; xbuf[t&1] from window t-1 already ready

    if (isH && sub == 1 && w >= 1) {
      // ---- epilogue (both M-tiles) ----
      u64_t pk[2]; float hh[2];
      #pragma unroll
      for (int mt = 0; mt < 2; ++mt) {
        f32x4 a = acc[mt];
        a += *(const f32x4*)&red[((ntile * 2 + mt) * 64 + lane) * 4];
        a += *(const f32x4*)&xbuf[(((((t & 1) * 2 + ntile) * 2 + 0) * 2 + mt) * 64 + lane) * 4];
        a += *(const f32x4*)&xbuf[(((((t & 1) * 2 + ntile) * 2 + 1) * 2 + mt) * 64 + lane) * 4];
        float pi = a[0] + bI[mt], pf = a[1] + bF[mt];
        float pg = a[2] + bG[mt], po = a[3] + bO[mt];
        float ig = sigm(pi), fg = sigm(pf), gg = fast_tanh(pg), og = sigm(po);
        c[mt] = fg * c[mt] + ig * gg;
        float h = og * fast_tanh(c[mt]);
        hh[mt] = h;
        unsigned v  = f2bf(h);
        unsigned v1 = __shfl((int)v, (lane & 15) + 16);
        unsigned v2 = __shfl((int)v, (lane & 15) + 32);
        unsigned v3 = __shfl((int)v, (lane & 15) + 48);
        pk[mt] = (u64_t)(v & 0xFFFFu) | ((u64_t)(v1 & 0xFFFFu) << 16)
               | ((u64_t)(v2 & 0xFFFFu) << 32) | ((u64_t)(v3 & 0xFFFFu) << 48);
      }
      if (t == SEQ - 1) {
        #pragma unroll
        for (int mt = 0; mt < 2; ++mt) {
          const int u = u0 + mt * 4;
          out[out_h_off + bb * 1024 + u] = hh[mt];
          out[out_c_off + bb * 1024 + u] = c[mt];
          if (write_last) out[bb * 1024 + u] = hh[mt];
        }
      }
      if (lane < 16) {
        u64_t* dst = (u64_t*)(hbuf_w + (long)(t + 1) * HSLOT + (long)bb * 1024 + ub);
        __hip_atomic_store(dst,     pk[0], __ATOMIC_RELAXED, __HIP_MEMORY_SCOPE_AGENT);
        __hip_atomic_store(dst + 1, pk[1], __ATOMIC_RELAXED, __HIP_MEMORY_SCOPE_AGENT);
      }
      asm volatile("s_waitcnt vmcnt(0)" ::: "memory");   // drain publish
    }

    if (!isH && w < SEQ) {
      // ---- x-prefetch for step s=w (off critical path, hidden under poll) ----
      const int s = w;
      f32x4 xa[2] = {{0.f,0.f,0.f,0.f},{0.f,0.f,0.f,0.f}};
      if constexpr (XFP32) {
        const float* bp = (const float*)xsrc + (long)s * x_step
                          + (long)bb * x_bstride + kbase + koff;
        f32x4 xv[2 * XCH];
        #pragma unroll
        for (int ch = 0; ch < XCH; ++ch) {
          xv[2*ch]   = *(const f32x4*)(bp + ch * 32);
          xv[2*ch+1] = *(const f32x4*)(bp + ch * 32 + 4);
        }
        #pragma unroll
        for (int ch = 0; ch < XCH; ++ch) {
          short8 bf = pack_bf8(xv[2*ch], xv[2*ch+1]);
          xa[0] = __builtin_amdgcn_mfma_f32_16x16x32_bf16(wreg[0][ch], bf, xa[0], 0, 0, 0);
          xa[1] = __builtin_amdgcn_mfma_f32_16x16x32_bf16(wreg[1][ch], bf, xa[1], 0, 0, 0);
        }
      } else {
        const ushort_t* bp = (const ushort_t*)xsrc + (long)s * x_step
                             + (long)bb * x_bstride + kbase + koff;
        short8 xv[16];
        #pragma unroll
        for (int ch = 0; ch < 16; ++ch) xv[ch] = *(const short8*)(bp + ch * 32);
        #pragma unroll
        for (int ch = 0; ch < 16; ++ch) {
          xa[0] = __builtin_amdgcn_mfma_f32_16x16x32_bf16(wreg[0][ch], xv[ch], xa[0], 0, 0, 0);
          xa[1] = __builtin_amdgcn_mfma_f32_16x16x32_bf16(wreg[1][ch], xv[ch], xa[1], 0, 0, 0);
        }
      }
      #pragma unroll
      for (int mt = 0; mt < 2; ++mt)
        *(f32x4*)&xbuf[(((((s & 1) * 2 + ntile) * 2 + (r - 2)) * 2 + mt) * 64 + lane) * 4] = xa[mt];
    }

    // barrier epoch e = w+2; gates window w+1 (needs O0 slot w+2 for L1 x)
    const unsigned e = (unsigned)(w + 2);
    const unsigned pt = (ISL1 && e <= 512u) ? (e + 2u) : 0u;
    bar_epoch(cntOwn, relOther, abortp, hcount, e, master, lidx, pt);
  }
}

__global__ __launch_bounds__(NTHREADS, 2)
void lstm_persistent(const float* __restrict__ x,  const float* __restrict__ W0,
                     const float* __restrict__ b0, const float* __restrict__ W1,
                     const float* __restrict__ b1, float* __restrict__ out,
                     unsigned* cnt, ushort_t* O0, ushort_t* H1)
{
  __shared__ float    xbuf[4096];   // [buf2][ntile2][xsub2][mt2][64][4] = 16 KB
  __shared__ float    red[1024];    // [ntile2][mt2][64][4] = 4 KB
  __shared__ unsigned hcount;
  const int  role = (int)(blockIdx.x >> 7);      // 0: layer0, 1: layer1
  const int  lidx = (int)(blockIdx.x & 127);
  const int  ub   = lidx * 8;
  const bool master = (lidx == 0);
  unsigned* cntOwn  = cnt + role * LBASE;
  unsigned* relOther= cnt + (1 - role) * LBASE + RELOFF;
  unsigned* abortp  = cnt + ABORT_U32;

  if (threadIdx.x == 0) hcount = 0;

  // zero own slice of slot 0 (this WG's publish region), device-visible (sc1)
  ushort_t* hb = role ? H1 : O0;
  if (threadIdx.x < 128) {
    int b = threadIdx.x >> 2, p = threadIdx.x & 3;
    __hip_atomic_store((unsigned*)hb + (long)b * 512 + (ub >> 1) + p, 0u,
                       __ATOMIC_RELAXED, __HIP_MEMORY_SCOPE_AGENT);
  }
  asm volatile("s_waitcnt vmcnt(0)" ::: "memory");
  __syncthreads();

  // init barrier (epoch 1); gates window 0 (L1 window 0 x needs O0 slot 1 ->
  // L0 release >= 3 = e+2)
  bar_epoch(cntOwn, relOther, abortp, &hcount, 1u, master, lidx,
            role ? 3u : 0u);

  if (role == 0) {
    run_layer<512, true, false>(x, 512, 262144,
                                O0, O0, W0, 1536, b0,
                                out, 32768, 98304, 0,
                                xbuf, red, &hcount, cntOwn, relOther, abortp,
                                lidx, ub, master);
  } else {
    // L1 x source: O0 shifted by one slot (window-w x reads O0 slot w+1)
    run_layer<1024, false, true>((const void*)(O0 + HSLOT), HSLOT, 1024,
                                 H1, H1, W1, 2048, b1,
                                 out, 65536, 131072, 1,
                                 xbuf, red, &hcount, cntOwn, relOther, abortp,
                                 lidx, ub, master);
  }
}

extern "C" void kernel_launch(void* const* d_in, const int* in_sizes, int n_in,
                              void* d_out, int out_size, void* d_ws, size_t ws_size,
                              hipStream_t stream) {
  (void)in_sizes; (void)n_in; (void)out_size;

  const float* x  = (const float*)d_in[0];
  const float* W0 = (const float*)d_in[1];
  const float* b0 = (const float*)d_in[2];
  const float* W1 = (const float*)d_in[3];
  const float* b1 = (const float*)d_in[4];
  float* out = (float*)d_out;

  // workspace:
  //   [0, 32K)            2 per-layer counter regions (stripes + release) + abort
  //   [32K, +513*64KB)    O0: layer-0 h slots (write-once)
  //   [.., +513*64KB)     H1: layer-1 h slots (write-once)
  const size_t hb_bytes = (size_t)FULLSLOTS * HSLOT * sizeof(ushort_t);
  const size_t need     = CNT_BYTES + 2 * hb_bytes;
  if (ws_size < need) return;  // wrong answer -> absmax signal, not a hang

  unsigned* cnt = (unsigned*)d_ws;
  ushort_t* O0  = (ushort_t*)((char*)d_ws + CNT_BYTES);
  ushort_t* H1  = O0 + (size_t)FULLSLOTS * HSLOT;

  hipMemsetAsync(d_ws, 0, CNT_BYTES, stream);

  lstm_persistent<<<dim3(NWG), dim3(NTHREADS), 0, stream>>>(
      x, W0, b0, W1, b1, out, cnt, O0, H1);
}